// Round 5
// baseline (718.044 us; speedup 1.0000x reference)
//
#include <hip/hip_runtime.h>
#include <hip/hip_bf16.h>
#include <math.h>

#define NTOK 16384
#define DM 1024
#define DFF 4096
#define NEXP 8
#define CAP 2560

typedef __bf16 bf16;
typedef float f32x4 __attribute__((ext_vector_type(4)));
typedef bf16 bf16x8 __attribute__((ext_vector_type(8)));
typedef bf16 bf16x4 __attribute__((ext_vector_type(4)));

// ---------------- workspace layout (bytes) ----------------
#define OFF_PROBS 0ull                 // E*N f32          = 524288
#define OFF_IDX   524288ull            // E*CAP i32        = 81920
#define OFF_WTS   606208ull            // E*CAP f32        = 81920
#define OFF_W1T   688128ull            // E*F*D bf16       = 67108864
#define OFF_W2T   67796992ull          // E*D*F bf16       = 67108864
#define OFF_X     134905856ull         // E*CAP*D bf16     = 41943040
#define OFF_ENT   OFF_X                // 4096 f32 (overlay: dead before gather writes X)
#define OFF_H     176848896ull         // fused: E*CAP*F bf16 = 167772160
#define WS_MIN    197820416ull
#define WS_FUSED  344621056ull

#define BAR() __builtin_amdgcn_s_barrier()

__device__ __forceinline__ void gl16(const bf16* g, const bf16* l) {
  __builtin_amdgcn_global_load_lds((const __attribute__((address_space(1))) void*)g,
                                   (__attribute__((address_space(3))) void*)l, 16, 0, 0);
}

// inline-asm ds_read_b128: invisible to the compiler's LDS-DMA dependency tracker,
// so it cannot insert conservative vmcnt(0) drains before fragment loads (the r4 stall).
// Correctness: explicit counted s_waitcnt vmcnt chain + lgkmcnt(0)+sched_barrier per phase.
__device__ __forceinline__ bf16x8 ldsrd16(const bf16* a) {
  bf16x8 d;
  asm volatile("ds_read_b128 %0, %1"
               : "=v"(d)
               : "v"((const __attribute__((address_space(3))) bf16*)a));
  return d;
}

__device__ __forceinline__ float gelu_f(float x) {
  // tanh-approx GELU via sigmoid; |err vs erf-gelu| < 4e-4 (validated r1-r4, absmax 2e-3)
  float u = 1.5957691216057308f * (x + 0.044715f * x * x * x);
  return x * __builtin_amdgcn_rcpf(1.f + __expf(-u));
}

// ---------------- transpose + convert fp32 -> bf16 ----------------
__global__ __launch_bounds__(256) void k_transpose_cvt(const float* __restrict__ src,
                                                       bf16* __restrict__ dst, int R, int C) {
  __shared__ float tile[64][69];
  int e = blockIdx.z;
  src += (size_t)e * R * C;
  dst += (size_t)e * R * C;
  int c0 = blockIdx.x * 64, r0 = blockIdx.y * 64;
  int t = threadIdx.x;
  int tr = t >> 4, tc4 = (t & 15) * 4;
#pragma unroll
  for (int i = 0; i < 4; i++) {
    int r = tr + i * 16;
    float4 v = *(const float4*)(src + (size_t)(r0 + r) * C + c0 + tc4);
    tile[r][tc4] = v.x; tile[r][tc4 + 1] = v.y; tile[r][tc4 + 2] = v.z; tile[r][tc4 + 3] = v.w;
  }
  __syncthreads();
#pragma unroll
  for (int i = 0; i < 4; i++) {
    int orr = tr + i * 16;
    bf16x4 o = {(bf16)tile[tc4][orr], (bf16)tile[tc4 + 1][orr],
                (bf16)tile[tc4 + 2][orr], (bf16)tile[tc4 + 3][orr]};
    *(bf16x4*)(dst + (size_t)(c0 + orr) * R + r0 + tc4) = o;
  }
}

// ---------------- router (fp-order stable since r1: selection set must be exact) --------
__global__ __launch_bounds__(256) void k_router(const float* __restrict__ hidden,
                                                const float* __restrict__ rw,
                                                float* __restrict__ probsT,
                                                float* __restrict__ entPart) {
  __shared__ float went[4];
  int wv = threadIdx.x >> 6, lane = threadIdx.x & 63;
  int token = blockIdx.x * 4 + wv;
  float acc[NEXP];
#pragma unroll
  for (int e = 0; e < NEXP; e++) acc[e] = 0.f;
  const float* hp = hidden + (size_t)token * DM;
  for (int d = lane; d < DM; d += 64) {
    float h = hp[d];
#pragma unroll
    for (int e = 0; e < NEXP; e++) acc[e] = fmaf(h, rw[d * NEXP + e], acc[e]);
  }
#pragma unroll
  for (int e = 0; e < NEXP; e++) {
    float v = acc[e];
#pragma unroll
    for (int s = 1; s < 64; s <<= 1) v += __shfl_xor(v, s);
    acc[e] = v;
  }
  float mx = acc[0];
#pragma unroll
  for (int e = 1; e < NEXP; e++) mx = fmaxf(mx, acc[e]);
  float p[NEXP], s = 0.f;
#pragma unroll
  for (int e = 0; e < NEXP; e++) { p[e] = expf(acc[e] - mx); s += p[e]; }
  float inv = 1.f / s;
  float ent = 0.f;
#pragma unroll
  for (int e = 0; e < NEXP; e++) { p[e] *= inv; ent += p[e] * logf(p[e] + 1e-8f); }
  if (lane < NEXP) probsT[(size_t)lane * NTOK + token] = p[lane];
  if (lane == 0) went[wv] = ent;
  __syncthreads();
  if (threadIdx.x == 0) entPart[blockIdx.x] = went[0] + went[1] + went[2] + went[3];
}

__global__ __launch_bounds__(256) void k_aux(const float* __restrict__ part, float* __restrict__ outAux) {
  __shared__ float s[256];
  int t = threadIdx.x;
  float v = 0.f;
#pragma unroll
  for (int i = 0; i < 16; i++) v += part[i * 256 + t];
  s[t] = v;
  __syncthreads();
  for (int st = 128; st > 0; st >>= 1) {
    if (t < st) s[t] += s[t + st];
    __syncthreads();
  }
  if (t == 0) outAux[0] = s[0] * (1.f / (float)NTOK);
}

// ---------------- exact top-k per expert ----------------
__global__ __launch_bounds__(1024) void k_topk(const float* __restrict__ probsT,
                                               int* __restrict__ idx,
                                               float* __restrict__ wts) {
  int e = blockIdx.x;
  const float* row = probsT + (size_t)e * NTOK;
  int t = threadIdx.x;
  unsigned u[16];
#pragma unroll
  for (int j = 0; j < 16; j++) u[j] = __float_as_uint(row[j * 1024 + t]);
  __shared__ int wred[16];
  __shared__ int bc;
  __shared__ int cnt_gt, cnt_eq;
  __shared__ int eqbuf[2048];
  int lane = t & 63, wv = t >> 6;
  unsigned prefix = 0;
  for (int bit = 30; bit >= 0; bit--) {
    unsigned cand = prefix | (1u << bit);
    int c = 0;
#pragma unroll
    for (int j = 0; j < 16; j++) c += (u[j] >= cand) ? 1 : 0;
#pragma unroll
    for (int s = 1; s < 64; s <<= 1) c += __shfl_xor(c, s);
    if (lane == 0) wred[wv] = c;
    __syncthreads();
    if (t == 0) { int tot = 0; for (int k = 0; k < 16; k++) tot += wred[k]; bc = tot; }
    __syncthreads();
    if (bc >= CAP) prefix = cand;
  }
  unsigned vC = prefix;
  if (t == 0) { cnt_gt = 0; cnt_eq = 0; }
  __syncthreads();
#pragma unroll
  for (int j = 0; j < 16; j++) {
    int i = j * 1024 + t;
    if (u[j] > vC) {
      int p = atomicAdd(&cnt_gt, 1);
      idx[e * CAP + p] = i;
      wts[e * CAP + p] = __uint_as_float(u[j]);
    } else if (u[j] == vC) {
      int p = atomicAdd(&cnt_eq, 1);
      if (p < 2048) eqbuf[p] = i;
    }
  }
  __syncthreads();
  int m = cnt_gt;
  int ne = cnt_eq > 2048 ? 2048 : cnt_eq;
  int needed = CAP - m;
  for (int j = t; j < ne; j += 1024) {
    int my = eqbuf[j];
    int rank = 0;
    for (int k = 0; k < ne; k++) rank += (eqbuf[k] < my) ? 1 : 0;
    if (rank < needed) {
      idx[e * CAP + m + rank] = my;
      wts[e * CAP + m + rank] = __uint_as_float(vC);
    }
  }
}

// ---------------- gather selected tokens -> bf16 ----------------
__global__ void k_gather(const float* __restrict__ hidden, const int* __restrict__ idx,
                         bf16* __restrict__ X) {
  int ec = blockIdx.x;
  int token = idx[ec];
  const float4* src = (const float4*)(hidden + (size_t)token * DM);
  bf16* dstrow = X + (size_t)ec * DM;
  int t = threadIdx.x;
  float4 v = src[t];
  bf16x4 o = {(bf16)v.x, (bf16)v.y, (bf16)v.z, (bf16)v.w};
  *(bf16x4*)(dstrow + t * 4) = o;
}

// ---------------- persistent 256x256 8-phase bf16 MFMA GEMM, asm ds_read ----------------
// 160 jobs/expert for both GEMMs (EPI0: 10 bx x 16 n-tiles; EPI1: 10 bx x 4 n x 4 k-split),
// 32 slots/expert x 5 assignments, pipeline continuous across assignment boundaries.
template <int EPI>
__global__ __launch_bounds__(512, 2) void k_gemm256p(
    const bf16* __restrict__ Ab, const bf16* __restrict__ Bb,
    bf16* __restrict__ Hb, const int* __restrict__ idxb, const float* __restrict__ wtsb,
    float* __restrict__ outb, int serialE) {
  constexpr int KD = (EPI == 0) ? DM : DFF;
  constexpr int NT = 16;  // K-tiles of 64 per assignment (EPI1: split-K=4 over DFF)

  __shared__ bf16 As[2][256 * 64];
  __shared__ bf16 Bs[2][256 * 64];

  int e, slot, nA;
  if (serialE >= 0) { e = serialE; slot = blockIdx.x; nA = 1; }
  else { e = blockIdx.x & 7; slot = blockIdx.x >> 3; nA = 5; }
  const bf16* A = Ab + (size_t)e * ((EPI == 0) ? (size_t)CAP * DM : (size_t)CAP * DFF);
  const bf16* B = Bb + (size_t)e * ((EPI == 0) ? (size_t)DFF * DM : (size_t)DM * DFF);

  int t = threadIdx.x, lane = t & 63, wv = t >> 6;
  int wm = wv >> 2, wn = wv & 3;
  int l3 = lane >> 3, l7 = lane & 7;
  int cswz = (l7 ^ l3) * 8;  // pre-swizzled global col offset (elems)

  auto decode = [&](int sq, int& m0_, int& n0_, int& k0_) {
    int s_ = sq / 40, r_ = sq % 40;
    m0_ = (r_ >> 2) * 256;
    if constexpr (EPI == 0) { n0_ = ((s_ << 2) + (r_ & 3)) * 256; k0_ = 0; }
    else { n0_ = (r_ & 3) * 256; k0_ = s_ * 1024; }
  };

  // half 0: A rows 0-63,128-191 (m-frags q0) ; half 1: B n-frags 0-1
  // half 2: B n-frags 2-3 ; half 3: A rows 64-127,192-255 (q1). 2 gl16/wave each.
  auto stage = [&](const bf16* Am, const bf16* Bn, int half, int ktE, int buf) {
#pragma unroll
    for (int j = 0; j < 2; ++j) {
      int u = wv * 2 + j;
      int rb; const bf16* G; bf16* L;
      if (half == 0)      { rb = u * 8 + (u >> 3) * 64;            G = Am + (size_t)(rb + l3) * KD; L = &As[buf][rb * 64]; }
      else if (half == 3) { rb = 64 + u * 8 + (u >> 3) * 64;       G = Am + (size_t)(rb + l3) * KD; L = &As[buf][rb * 64]; }
      else if (half == 1) { rb = (u >> 2) * 64 + (u & 3) * 8;      G = Bn + (size_t)(rb + l3) * KD; L = &Bs[buf][rb * 64]; }
      else                { rb = (u >> 2) * 64 + 32 + (u & 3) * 8; G = Bn + (size_t)(rb + l3) * KD; L = &Bs[buf][rb * 64]; }
      gl16(G + ktE + cswz, L + lane * 8);
    }
  };

  auto rdA = [&](const bf16* base, int q, int i, int kk) -> bf16x8 {
    int rr = wm * 128 + (q * 4 + i) * 16 + (lane & 15);
    int slt = (kk * 4 + (lane >> 4)) ^ l7;
    return ldsrd16((const bf16*)((const char*)base + rr * 128 + slt * 16));
  };
  auto rdB = [&](const bf16* base, int h, int i, int kk) -> bf16x8 {
    int rr = wn * 64 + (h * 2 + i) * 16 + (lane & 15);
    int slt = (kk * 4 + (lane >> 4)) ^ l7;
    return ldsrd16((const bf16*)((const char*)base + rr * 128 + slt * 16));
  };

  f32x4 acc[8][4];
#pragma unroll
  for (int m = 0; m < 8; m++)
#pragma unroll
    for (int n = 0; n < 4; n++) acc[m][n] = (f32x4){0.f, 0.f, 0.f, 0.f};
  bf16x8 aF[4][2], bF0[2][2], bF1[2][2];

  int seq = slot;
  int m0, n0, k0;
  decode(seq, m0, n0, k0);
  const bf16* Am = A + (size_t)m0 * KD;
  const bf16* Bn = B + (size_t)n0 * KD;

  // prologue: tile 0 -> buf0 ; after vmcnt(4): halves 0,1 landed, 2,3 in flight
  stage(Am, Bn, 0, k0, 0); stage(Am, Bn, 1, k0, 0);
  stage(Am, Bn, 2, k0, 0); stage(Am, Bn, 3, k0, 0);
  asm volatile("s_waitcnt vmcnt(4)");
  BAR();

  for (int a = 0; a < nA; ++a) {
    int m0N = 0, n0N = 0, k0N = 0;
    const bf16 *AmN = nullptr, *BnN = nullptr;
    bool hasNextA = (a + 1 < nA);
    if (hasNextA) {
      decode(seq + 32, m0N, n0N, k0N);
      AmN = A + (size_t)m0N * KD;
      BnN = B + (size_t)n0N * KD;
    }
    for (int kt = 0; kt < NT; ++kt) {
      int cur = kt & 1;
      bool lastT = (kt == NT - 1);
      bool nl = !lastT || hasNextA;
      const bf16* sA = lastT ? AmN : Am;
      const bf16* sB = lastT ? BnN : Bn;
      int sk = lastT ? k0N : (k0 + (kt + 1) * 64);

      // ---- p0: rd A q0 + B h0 ; stage h0(next) ; mfma m0-3 x n0-1 ----
#pragma unroll
      for (int i = 0; i < 4; i++)
#pragma unroll
        for (int kk = 0; kk < 2; kk++) aF[i][kk] = rdA(As[cur], 0, i, kk);
#pragma unroll
      for (int i = 0; i < 2; i++)
#pragma unroll
        for (int kk = 0; kk < 2; kk++) bF0[i][kk] = rdB(Bs[cur], 0, i, kk);
      if (nl) stage(sA, sB, 0, sk, cur ^ 1);
      BAR();
      asm volatile("s_waitcnt lgkmcnt(0)");
      __builtin_amdgcn_sched_barrier(0);
      __builtin_amdgcn_s_setprio(1);
#pragma unroll
      for (int i = 0; i < 4; i++)
#pragma unroll
        for (int j = 0; j < 2; j++)
#pragma unroll
          for (int kk = 0; kk < 2; kk++)
            acc[i][j] = __builtin_amdgcn_mfma_f32_16x16x32_bf16(aF[i][kk], bF0[j][kk], acc[i][j], 0, 0, 0);
      __builtin_amdgcn_s_setprio(0);
      if (nl) asm volatile("s_waitcnt vmcnt(4)");   // h2(cur) landed
      else    asm volatile("s_waitcnt vmcnt(2)");
      BAR();
      // ---- p1: rd B h1 ; stage h1(next) ; mfma m0-3 x n2-3 ----
#pragma unroll
      for (int i = 0; i < 2; i++)
#pragma unroll
        for (int kk = 0; kk < 2; kk++) bF1[i][kk] = rdB(Bs[cur], 1, i, kk);
      if (nl) stage(sA, sB, 1, sk, cur ^ 1);
      BAR();
      asm volatile("s_waitcnt lgkmcnt(0)");
      __builtin_amdgcn_sched_barrier(0);
      __builtin_amdgcn_s_setprio(1);
#pragma unroll
      for (int i = 0; i < 4; i++)
#pragma unroll
        for (int j = 0; j < 2; j++)
#pragma unroll
          for (int kk = 0; kk < 2; kk++)
            acc[i][2 + j] = __builtin_amdgcn_mfma_f32_16x16x32_bf16(aF[i][kk], bF1[j][kk], acc[i][2 + j], 0, 0, 0);
      __builtin_amdgcn_s_setprio(0);
      if (nl) asm volatile("s_waitcnt vmcnt(4)");   // h3(cur) landed
      else    asm volatile("s_waitcnt vmcnt(0)");
      BAR();
      // ---- p2: rd A q1 ; stage h2(next) ; mfma m4-7 x n0-1 ----
#pragma unroll
      for (int i = 0; i < 4; i++)
#pragma unroll
        for (int kk = 0; kk < 2; kk++) aF[i][kk] = rdA(As[cur], 1, i, kk);
      if (nl) stage(sA, sB, 2, sk, cur ^ 1);
      BAR();
      asm volatile("s_waitcnt lgkmcnt(0)");
      __builtin_amdgcn_sched_barrier(0);
      __builtin_amdgcn_s_setprio(1);
#pragma unroll
      for (int i = 0; i < 4; i++)
#pragma unroll
        for (int j = 0; j < 2; j++)
#pragma unroll
          for (int kk = 0; kk < 2; kk++)
            acc[4 + i][j] = __builtin_amdgcn_mfma_f32_16x16x32_bf16(aF[i][kk], bF0[j][kk], acc[4 + i][j], 0, 0, 0);
      __builtin_amdgcn_s_setprio(0);
      BAR();
      // ---- p3: stage h3(next) ; mfma m4-7 x n2-3 ----
      if (nl) stage(sA, sB, 3, sk, cur ^ 1);
      BAR();
      __builtin_amdgcn_s_setprio(1);
#pragma unroll
      for (int i = 0; i < 4; i++)
#pragma unroll
        for (int j = 0; j < 2; j++)
#pragma unroll
          for (int kk = 0; kk < 2; kk++)
            acc[4 + i][2 + j] = __builtin_amdgcn_mfma_f32_16x16x32_bf16(aF[i][kk], bF1[j][kk], acc[4 + i][2 + j], 0, 0, 0);
      __builtin_amdgcn_s_setprio(0);
      if (nl) asm volatile("s_waitcnt vmcnt(4)");   // h0,h1(next) landed
      BAR();
    }

    // ---- epilogue (no LDS; next-assignment loads in flight; stores join vmcnt FIFO,
    //      so the next vmcnt(4) transitively proves h2/h3 landed — counted-chain safe) ----
    int cl = lane & 15, rg = (lane >> 4) * 4;
    if constexpr (EPI == 0) {
      bf16* He = Hb + (size_t)e * CAP * DFF;
#pragma unroll
      for (int m = 0; m < 8; m++) {
        int rowg = m0 + wm * 128 + m * 16 + rg;
#pragma unroll
        for (int n = 0; n < 4; n++) {
          int col = n0 + wn * 64 + n * 16 + cl;
#pragma unroll
          for (int rr = 0; rr < 4; rr++)
            He[(size_t)(rowg + rr) * DFF + col] = (bf16)gelu_f(acc[m][n][rr]);
        }
      }
    } else {
      const int* idxE = idxb + e * CAP;
      const float* wtsE = wtsb + e * CAP;
#pragma unroll
      for (int m = 0; m < 8; m++) {
        int rowg = m0 + wm * 128 + m * 16 + rg;
#pragma unroll
        for (int rr = 0; rr < 4; rr++) {
          int c = rowg + rr;
          int token = idxE[c];
          float w = wtsE[c];
          float* op = outb + (size_t)token * DM + n0 + wn * 64 + cl;
#pragma unroll
          for (int n = 0; n < 4; n++) atomicAdd(op + n * 16, w * acc[m][n][rr]);
        }
      }
    }
#pragma unroll
    for (int m = 0; m < 8; m++)
#pragma unroll
      for (int n = 0; n < 4; n++) acc[m][n] = (f32x4){0.f, 0.f, 0.f, 0.f};

    if (hasNextA) { m0 = m0N; n0 = n0N; k0 = k0N; Am = AmN; Bn = BnN; seq += 32; }
  }
}

extern "C" void kernel_launch(void* const* d_in, const int* in_sizes, int n_in,
                              void* d_out, int out_size, void* d_ws, size_t ws_size,
                              hipStream_t stream) {
  const float* hidden = (const float*)d_in[0];
  const float* router_w = (const float*)d_in[1];
  const float* W1 = (const float*)d_in[2];
  const float* W2 = (const float*)d_in[3];
  float* out = (float*)d_out;
  if (ws_size < WS_MIN) return;

  char* ws = (char*)d_ws;
  float* probsT = (float*)(ws + OFF_PROBS);
  int* idxb = (int*)(ws + OFF_IDX);
  float* wtsb = (float*)(ws + OFF_WTS);
  bf16* W1T = (bf16*)(ws + OFF_W1T);
  bf16* W2T = (bf16*)(ws + OFF_W2T);
  bf16* Xall = (bf16*)(ws + OFF_X);
  float* entPart = (float*)(ws + OFF_ENT);
  bf16* Hbuf = (bf16*)(ws + OFF_H);

  hipMemsetAsync(d_out, 0, (size_t)out_size * sizeof(float), stream);

  k_transpose_cvt<<<dim3(DFF / 64, DM / 64, NEXP), 256, 0, stream>>>(W1, W1T, DM, DFF);
  k_transpose_cvt<<<dim3(DM / 64, DFF / 64, NEXP), 256, 0, stream>>>(W2, W2T, DFF, DM);

  k_router<<<NTOK / 4, 256, 0, stream>>>(hidden, router_w, probsT, entPart);
  k_aux<<<1, 256, 0, stream>>>(entPart, out + (size_t)NTOK * DM);
  k_topk<<<NEXP, 1024, 0, stream>>>(probsT, idxb, wtsb);
  k_gather<<<NEXP * CAP, 256, 0, stream>>>(hidden, idxb, Xall);

  if (ws_size >= WS_FUSED) {
    k_gemm256p<0><<<256, 512, 0, stream>>>(Xall, W1T, Hbuf, nullptr, nullptr, nullptr, -1);
    k_gemm256p<1><<<256, 512, 0, stream>>>(Hbuf, W2T, nullptr, idxb, wtsb, out, -1);
  } else {
    for (int e = 0; e < NEXP; e++) {
      bf16* Hadj = Hbuf - (size_t)e * CAP * DFF;  // cancels the e-offset inside the kernel
      k_gemm256p<0><<<160, 512, 0, stream>>>(Xall, W1T, Hadj, nullptr, nullptr, nullptr, e);
      k_gemm256p<1><<<160, 512, 0, stream>>>(Hadj, W2T, nullptr, idxb, wtsb, out, e);
    }
  }
}

// Round 6
// 661.570 us; speedup vs baseline: 1.0854x; 1.0854x over previous
//
#include <hip/hip_runtime.h>
#include <hip/hip_bf16.h>
#include <math.h>

#define NTOK 16384
#define DM 1024
#define DFF 4096
#define NEXP 8
#define CAP 2560

typedef __bf16 bf16;
typedef float f32x4 __attribute__((ext_vector_type(4)));
typedef bf16 bf16x8 __attribute__((ext_vector_type(8)));
typedef bf16 bf16x4 __attribute__((ext_vector_type(4)));

// ---------------- workspace layout (bytes) ----------------
#define OFF_PROBS 0ull                 // E*N f32          = 524288
#define OFF_IDX   524288ull            // E*CAP i32        = 81920
#define OFF_WTS   606208ull            // E*CAP f32        = 81920
#define OFF_W1T   688128ull            // E*F*D bf16       = 67108864
#define OFF_W2T   67796992ull          // E*D*F bf16       = 67108864
#define OFF_X     134905856ull         // E*CAP*D bf16     = 41943040
#define OFF_ENT   OFF_X                // 4096 f32 (overlay: dead before gather writes X)
#define OFF_H     176848896ull         // fused: E*CAP*F bf16 = 167772160
#define WS_MIN    197820416ull
#define WS_FUSED  344621056ull

__device__ __forceinline__ void gl16(const bf16* g, const bf16* l) {
  __builtin_amdgcn_global_load_lds((const __attribute__((address_space(1))) void*)g,
                                   (__attribute__((address_space(3))) void*)l, 16, 0, 0);
}

__device__ __forceinline__ float gelu_f(float x) {
  // tanh-approx GELU via sigmoid; |err vs erf-gelu| < 4e-4 (validated r1-r5, absmax 2e-3)
  float u = 1.5957691216057308f * (x + 0.044715f * x * x * x);
  return x * __builtin_amdgcn_rcpf(1.f + __expf(-u));
}

// ---------------- transpose + convert fp32 -> bf16 ----------------
__global__ __launch_bounds__(256) void k_transpose_cvt(const float* __restrict__ src,
                                                       bf16* __restrict__ dst, int R, int C) {
  __shared__ float tile[64][69];
  int e = blockIdx.z;
  src += (size_t)e * R * C;
  dst += (size_t)e * R * C;
  int c0 = blockIdx.x * 64, r0 = blockIdx.y * 64;
  int t = threadIdx.x;
  int tr = t >> 4, tc4 = (t & 15) * 4;
#pragma unroll
  for (int i = 0; i < 4; i++) {
    int r = tr + i * 16;
    float4 v = *(const float4*)(src + (size_t)(r0 + r) * C + c0 + tc4);
    tile[r][tc4] = v.x; tile[r][tc4 + 1] = v.y; tile[r][tc4 + 2] = v.z; tile[r][tc4 + 3] = v.w;
  }
  __syncthreads();
#pragma unroll
  for (int i = 0; i < 4; i++) {
    int orr = tr + i * 16;
    bf16x4 o = {(bf16)tile[tc4][orr], (bf16)tile[tc4 + 1][orr],
                (bf16)tile[tc4 + 2][orr], (bf16)tile[tc4 + 3][orr]};
    *(bf16x4*)(dst + (size_t)(c0 + orr) * R + r0 + tc4) = o;
  }
}

// ---------------- router (fp-order stable since r1: selection set must be exact) --------
__global__ __launch_bounds__(256) void k_router(const float* __restrict__ hidden,
                                                const float* __restrict__ rw,
                                                float* __restrict__ probsT,
                                                float* __restrict__ entPart) {
  __shared__ float went[4];
  int wv = threadIdx.x >> 6, lane = threadIdx.x & 63;
  int token = blockIdx.x * 4 + wv;
  float acc[NEXP];
#pragma unroll
  for (int e = 0; e < NEXP; e++) acc[e] = 0.f;
  const float* hp = hidden + (size_t)token * DM;
  for (int d = lane; d < DM; d += 64) {
    float h = hp[d];
#pragma unroll
    for (int e = 0; e < NEXP; e++) acc[e] = fmaf(h, rw[d * NEXP + e], acc[e]);
  }
#pragma unroll
  for (int e = 0; e < NEXP; e++) {
    float v = acc[e];
#pragma unroll
    for (int s = 1; s < 64; s <<= 1) v += __shfl_xor(v, s);
    acc[e] = v;
  }
  float mx = acc[0];
#pragma unroll
  for (int e = 1; e < NEXP; e++) mx = fmaxf(mx, acc[e]);
  float p[NEXP], s = 0.f;
#pragma unroll
  for (int e = 0; e < NEXP; e++) { p[e] = expf(acc[e] - mx); s += p[e]; }
  float inv = 1.f / s;
  float ent = 0.f;
#pragma unroll
  for (int e = 0; e < NEXP; e++) { p[e] *= inv; ent += p[e] * logf(p[e] + 1e-8f); }
  if (lane < NEXP) probsT[(size_t)lane * NTOK + token] = p[lane];
  if (lane == 0) went[wv] = ent;
  __syncthreads();
  if (threadIdx.x == 0) entPart[blockIdx.x] = went[0] + went[1] + went[2] + went[3];
}

__global__ __launch_bounds__(256) void k_aux(const float* __restrict__ part, float* __restrict__ outAux) {
  __shared__ float s[256];
  int t = threadIdx.x;
  float v = 0.f;
#pragma unroll
  for (int i = 0; i < 16; i++) v += part[i * 256 + t];
  s[t] = v;
  __syncthreads();
  for (int st = 128; st > 0; st >>= 1) {
    if (t < st) s[t] += s[t + st];
    __syncthreads();
  }
  if (t == 0) outAux[0] = s[0] * (1.f / (float)NTOK);
}

// ---------------- exact top-k per expert ----------------
__global__ __launch_bounds__(1024) void k_topk(const float* __restrict__ probsT,
                                               int* __restrict__ idx,
                                               float* __restrict__ wts) {
  int e = blockIdx.x;
  const float* row = probsT + (size_t)e * NTOK;
  int t = threadIdx.x;
  unsigned u[16];
#pragma unroll
  for (int j = 0; j < 16; j++) u[j] = __float_as_uint(row[j * 1024 + t]);
  __shared__ int wred[16];
  __shared__ int bc;
  __shared__ int cnt_gt, cnt_eq;
  __shared__ int eqbuf[2048];
  int lane = t & 63, wv = t >> 6;
  unsigned prefix = 0;
  for (int bit = 30; bit >= 0; bit--) {
    unsigned cand = prefix | (1u << bit);
    int c = 0;
#pragma unroll
    for (int j = 0; j < 16; j++) c += (u[j] >= cand) ? 1 : 0;
#pragma unroll
    for (int s = 1; s < 64; s <<= 1) c += __shfl_xor(c, s);
    if (lane == 0) wred[wv] = c;
    __syncthreads();
    if (t == 0) { int tot = 0; for (int k = 0; k < 16; k++) tot += wred[k]; bc = tot; }
    __syncthreads();
    if (bc >= CAP) prefix = cand;
  }
  unsigned vC = prefix;
  if (t == 0) { cnt_gt = 0; cnt_eq = 0; }
  __syncthreads();
#pragma unroll
  for (int j = 0; j < 16; j++) {
    int i = j * 1024 + t;
    if (u[j] > vC) {
      int p = atomicAdd(&cnt_gt, 1);
      idx[e * CAP + p] = i;
      wts[e * CAP + p] = __uint_as_float(u[j]);
    } else if (u[j] == vC) {
      int p = atomicAdd(&cnt_eq, 1);
      if (p < 2048) eqbuf[p] = i;
    }
  }
  __syncthreads();
  int m = cnt_gt;
  int ne = cnt_eq > 2048 ? 2048 : cnt_eq;
  int needed = CAP - m;
  for (int j = t; j < ne; j += 1024) {
    int my = eqbuf[j];
    int rank = 0;
    for (int k = 0; k < ne; k++) rank += (eqbuf[k] < my) ? 1 : 0;
    if (rank < needed) {
      idx[e * CAP + m + rank] = my;
      wts[e * CAP + m + rank] = __uint_as_float(vC);
    }
  }
}

// ---------------- gather selected tokens -> bf16 ----------------
__global__ void k_gather(const float* __restrict__ hidden, const int* __restrict__ idx,
                         bf16* __restrict__ X) {
  int ec = blockIdx.x;
  int token = idx[ec];
  const float4* src = (const float4*)(hidden + (size_t)token * DM);
  bf16* dstrow = X + (size_t)ec * DM;
  int t = threadIdx.x;
  float4 v = src[t];
  bf16x4 o = {(bf16)v.x, (bf16)v.y, (bf16)v.z, (bf16)v.w};
  *(bf16x4*)(dstrow + t * 4) = o;
}

// ---------------- m97-faithful 128x128 bf16 MFMA GEMM ----------------
// 256 threads (4 waves, 2x2), single-buffered 32 KiB LDS -> 3+ blocks/CU, plain
// __syncthreads(), compiler-managed waitcnts (m97 recipe: multi-block TLP does the
// overlap). Kept from r3: 0-conflict XOR swizzle (pre-swizzled gl_lds source cols,
// XOR'd fragment-read slots). Block order: expert = XCD (bid&7), bx-inner so
// co-resident blocks share the B-panel (L2-resident).
// EPI 0: e x (20 bx x 32 by), KD=DM,  NT=16, H = gelu(X*W1T)  [grid 5120]
// EPI 1: e x (20 bx x 8 by x 2 ksplit), KD=DFF, NT=32, atomic scatter [grid 2560]
template <int EPI>
__global__ __launch_bounds__(256) void k_gemm128(
    const bf16* __restrict__ Ab, const bf16* __restrict__ Bb,
    bf16* __restrict__ Hb, const int* __restrict__ idxb, const float* __restrict__ wtsb,
    float* __restrict__ outb, int serialE) {
  constexpr int KD = (EPI == 0) ? DM : DFF;
  constexpr int NT = (EPI == 0) ? 16 : 32;

  __shared__ bf16 As[128 * 64];
  __shared__ bf16 Bs[128 * 64];

  int e, j;
  if (serialE >= 0) { e = serialE; j = blockIdx.x; }
  else { e = blockIdx.x & 7; j = blockIdx.x >> 3; }
  int bx = j % 20, jr = j / 20;
  int m0 = bx * 128, n0, k0;
  if constexpr (EPI == 0) { n0 = jr * 128; k0 = 0; }
  else { n0 = (jr & 7) * 128; k0 = (jr >> 3) * 2048; }

  const bf16* A = Ab + (size_t)e * ((size_t)CAP * KD) + (size_t)m0 * KD;
  const bf16* B = Bb + (size_t)e * ((size_t)DFF * DM) + (size_t)n0 * KD;

  int t = threadIdx.x, lane = t & 63, wv = t >> 6;
  int wm = wv >> 1, wn = wv & 1;
  int l3 = lane >> 3, l7 = lane & 7;
  int cswz = (l7 ^ l3) * 8;  // pre-swizzled global col offset (elems)

  f32x4 acc[4][4];
#pragma unroll
  for (int m = 0; m < 4; m++)
#pragma unroll
    for (int n = 0; n < 4; n++) acc[m][n] = (f32x4){0.f, 0.f, 0.f, 0.f};

  // staging: chunk c = wv*4+jj covers rows c*8..c*8+7; lane -> row c*8+l3, slot l7.
  // LDS(row r, slot s) holds global k-chunk (s ^ (r&7)) -- swizzled content, linear dest.
  const bf16* gA0 = A + (size_t)(wv * 32 + l3) * KD + cswz;
  const bf16* gB0 = B + (size_t)(wv * 32 + l3) * KD + cswz;
  bf16* lA0 = As + wv * 2048 + lane * 8;
  bf16* lB0 = Bs + wv * 2048 + lane * 8;

  for (int kt = 0; kt < NT; kt++) {
    int ke = k0 + kt * 64;
#pragma unroll
    for (int jj = 0; jj < 4; jj++) {
      gl16(gA0 + (size_t)jj * 8 * KD + ke, lA0 + jj * 512);
      gl16(gB0 + (size_t)jj * 8 * KD + ke, lB0 + jj * 512);
    }
    __syncthreads();
#pragma unroll
    for (int kk = 0; kk < 2; kk++) {
      int kslot = kk * 4 + (lane >> 4);
      int slt = (kslot ^ l7) * 16;
      bf16x8 af[4], bfm[4];
#pragma unroll
      for (int m = 0; m < 4; m++) {
        int rr = wm * 64 + m * 16 + (lane & 15);
        af[m] = *(const bf16x8*)((const char*)As + rr * 128 + slt);
      }
#pragma unroll
      for (int n = 0; n < 4; n++) {
        int rr = wn * 64 + n * 16 + (lane & 15);
        bfm[n] = *(const bf16x8*)((const char*)Bs + rr * 128 + slt);
      }
#pragma unroll
      for (int m = 0; m < 4; m++)
#pragma unroll
        for (int n = 0; n < 4; n++)
          acc[m][n] = __builtin_amdgcn_mfma_f32_16x16x32_bf16(af[m], bfm[n], acc[m][n], 0, 0, 0);
    }
    __syncthreads();
  }

  int cl = lane & 15, rg = (lane >> 4) * 4;
  if constexpr (EPI == 0) {
    bf16* He = Hb + (size_t)e * CAP * DFF;
#pragma unroll
    for (int m = 0; m < 4; m++) {
      int rowg = m0 + wm * 64 + m * 16 + rg;
#pragma unroll
      for (int n = 0; n < 4; n++) {
        int col = n0 + wn * 64 + n * 16 + cl;
#pragma unroll
        for (int rr = 0; rr < 4; rr++)
          He[(size_t)(rowg + rr) * DFF + col] = (bf16)gelu_f(acc[m][n][rr]);
      }
    }
  } else {
    const int* idxE = idxb + e * CAP;
    const float* wtsE = wtsb + e * CAP;
#pragma unroll
    for (int m = 0; m < 4; m++) {
      int rowg = m0 + wm * 64 + m * 16 + rg;
#pragma unroll
      for (int rr = 0; rr < 4; rr++) {
        int c = rowg + rr;
        int token = idxE[c];
        float w = wtsE[c];
        float* op = outb + (size_t)token * DM + n0 + wn * 64 + cl;
#pragma unroll
        for (int n = 0; n < 4; n++) atomicAdd(op + n * 16, w * acc[m][n][rr]);
      }
    }
  }
}

extern "C" void kernel_launch(void* const* d_in, const int* in_sizes, int n_in,
                              void* d_out, int out_size, void* d_ws, size_t ws_size,
                              hipStream_t stream) {
  const float* hidden = (const float*)d_in[0];
  const float* router_w = (const float*)d_in[1];
  const float* W1 = (const float*)d_in[2];
  const float* W2 = (const float*)d_in[3];
  float* out = (float*)d_out;
  if (ws_size < WS_MIN) return;

  char* ws = (char*)d_ws;
  float* probsT = (float*)(ws + OFF_PROBS);
  int* idxb = (int*)(ws + OFF_IDX);
  float* wtsb = (float*)(ws + OFF_WTS);
  bf16* W1T = (bf16*)(ws + OFF_W1T);
  bf16* W2T = (bf16*)(ws + OFF_W2T);
  bf16* Xall = (bf16*)(ws + OFF_X);
  float* entPart = (float*)(ws + OFF_ENT);
  bf16* Hbuf = (bf16*)(ws + OFF_H);

  hipMemsetAsync(d_out, 0, (size_t)out_size * sizeof(float), stream);

  k_transpose_cvt<<<dim3(DFF / 64, DM / 64, NEXP), 256, 0, stream>>>(W1, W1T, DM, DFF);
  k_transpose_cvt<<<dim3(DM / 64, DFF / 64, NEXP), 256, 0, stream>>>(W2, W2T, DFF, DM);

  k_router<<<NTOK / 4, 256, 0, stream>>>(hidden, router_w, probsT, entPart);
  k_aux<<<1, 256, 0, stream>>>(entPart, out + (size_t)NTOK * DM);
  k_topk<<<NEXP, 1024, 0, stream>>>(probsT, idxb, wtsb);
  k_gather<<<NEXP * CAP, 256, 0, stream>>>(hidden, idxb, Xall);

  if (ws_size >= WS_FUSED) {
    k_gemm128<0><<<NEXP * 20 * 32, 256, 0, stream>>>(Xall, W1T, Hbuf, nullptr, nullptr, nullptr, -1);
    k_gemm128<1><<<NEXP * 20 * 16, 256, 0, stream>>>(Hbuf, W2T, nullptr, idxb, wtsb, out, -1);
  } else {
    for (int e = 0; e < NEXP; e++) {
      bf16* Hadj = Hbuf - (size_t)e * CAP * DFF;  // cancels the e-offset inside the kernel
      k_gemm128<0><<<20 * 32, 256, 0, stream>>>(Xall, W1T, Hadj, nullptr, nullptr, nullptr, e);
      k_gemm128<1><<<20 * 16, 256, 0, stream>>>(Hadj, W2T, nullptr, idxb, wtsb, out, e);
    }
  }
}

// Round 7
// 617.747 us; speedup vs baseline: 1.1624x; 1.0709x over previous
//
#include <hip/hip_runtime.h>
#include <hip/hip_bf16.h>
#include <math.h>

#define NTOK 16384
#define DM 1024
#define DFF 4096
#define NEXP 8
#define CAP 2560

typedef __bf16 bf16;
typedef float f32x4 __attribute__((ext_vector_type(4)));
typedef bf16 bf16x8 __attribute__((ext_vector_type(8)));
typedef bf16 bf16x4 __attribute__((ext_vector_type(4)));

// ---------------- workspace layout (bytes) ----------------
#define OFF_PROBS 0ull                 // E*N f32          = 524288
#define OFF_IDX   524288ull            // E*CAP i32        = 81920
#define OFF_WTS   606208ull            // E*CAP f32        = 81920
#define OFF_W1T   688128ull            // E*F*D bf16       = 67108864
#define OFF_W2T   67796992ull          // E*D*F bf16       = 67108864
#define OFF_X     134905856ull         // E*CAP*D bf16     = 41943040
#define OFF_ENT   OFF_X                // 4096 f32 (overlay: dead before gather writes X)
#define OFF_H     176848896ull         // fused: E*CAP*F bf16 = 167772160
#define WS_MIN    197820416ull
#define WS_FUSED  344621056ull

__device__ __forceinline__ void gl16(const bf16* g, const bf16* l) {
  __builtin_amdgcn_global_load_lds((const __attribute__((address_space(1))) void*)g,
                                   (__attribute__((address_space(3))) void*)l, 16, 0, 0);
}

// inline-asm ds_read_b128: invisible to the compiler's LDS-DMA alias tracking, so it
// cannot re-insert a vmcnt(0) drain before fragment reads while staging loads are in
// flight. Ordering is enforced by the explicit counted vmcnt + lgkmcnt(0)+sched_barrier.
__device__ __forceinline__ bf16x8 ldsrd16(const bf16* a) {
  bf16x8 d;
  asm volatile("ds_read_b128 %0, %1"
               : "=v"(d)
               : "v"((const __attribute__((address_space(3))) bf16*)a));
  return d;
}

__device__ __forceinline__ float gelu_f(float x) {
  // tanh-approx GELU via sigmoid; |err vs erf-gelu| < 4e-4 (validated r1-r6, absmax 2e-3)
  float u = 1.5957691216057308f * (x + 0.044715f * x * x * x);
  return x * __builtin_amdgcn_rcpf(1.f + __expf(-u));
}

// ---------------- transpose + convert fp32 -> bf16 ----------------
__global__ __launch_bounds__(256) void k_transpose_cvt(const float* __restrict__ src,
                                                       bf16* __restrict__ dst, int R, int C) {
  __shared__ float tile[64][69];
  int e = blockIdx.z;
  src += (size_t)e * R * C;
  dst += (size_t)e * R * C;
  int c0 = blockIdx.x * 64, r0 = blockIdx.y * 64;
  int t = threadIdx.x;
  int tr = t >> 4, tc4 = (t & 15) * 4;
#pragma unroll
  for (int i = 0; i < 4; i++) {
    int r = tr + i * 16;
    float4 v = *(const float4*)(src + (size_t)(r0 + r) * C + c0 + tc4);
    tile[r][tc4] = v.x; tile[r][tc4 + 1] = v.y; tile[r][tc4 + 2] = v.z; tile[r][tc4 + 3] = v.w;
  }
  __syncthreads();
#pragma unroll
  for (int i = 0; i < 4; i++) {
    int orr = tr + i * 16;
    bf16x4 o = {(bf16)tile[tc4][orr], (bf16)tile[tc4 + 1][orr],
                (bf16)tile[tc4 + 2][orr], (bf16)tile[tc4 + 3][orr]};
    *(bf16x4*)(dst + (size_t)(c0 + orr) * R + r0 + tc4) = o;
  }
}

// ---------------- router (fp-order stable since r1: selection set must be exact) --------
__global__ __launch_bounds__(256) void k_router(const float* __restrict__ hidden,
                                                const float* __restrict__ rw,
                                                float* __restrict__ probsT,
                                                float* __restrict__ entPart) {
  __shared__ float went[4];
  int wv = threadIdx.x >> 6, lane = threadIdx.x & 63;
  int token = blockIdx.x * 4 + wv;
  float acc[NEXP];
#pragma unroll
  for (int e = 0; e < NEXP; e++) acc[e] = 0.f;
  const float* hp = hidden + (size_t)token * DM;
  for (int d = lane; d < DM; d += 64) {
    float h = hp[d];
#pragma unroll
    for (int e = 0; e < NEXP; e++) acc[e] = fmaf(h, rw[d * NEXP + e], acc[e]);
  }
#pragma unroll
  for (int e = 0; e < NEXP; e++) {
    float v = acc[e];
#pragma unroll
    for (int s = 1; s < 64; s <<= 1) v += __shfl_xor(v, s);
    acc[e] = v;
  }
  float mx = acc[0];
#pragma unroll
  for (int e = 1; e < NEXP; e++) mx = fmaxf(mx, acc[e]);
  float p[NEXP], s = 0.f;
#pragma unroll
  for (int e = 0; e < NEXP; e++) { p[e] = expf(acc[e] - mx); s += p[e]; }
  float inv = 1.f / s;
  float ent = 0.f;
#pragma unroll
  for (int e = 0; e < NEXP; e++) { p[e] *= inv; ent += p[e] * logf(p[e] + 1e-8f); }
  if (lane < NEXP) probsT[(size_t)lane * NTOK + token] = p[lane];
  if (lane == 0) went[wv] = ent;
  __syncthreads();
  if (threadIdx.x == 0) entPart[blockIdx.x] = went[0] + went[1] + went[2] + went[3];
}

__global__ __launch_bounds__(256) void k_aux(const float* __restrict__ part, float* __restrict__ outAux) {
  __shared__ float s[256];
  int t = threadIdx.x;
  float v = 0.f;
#pragma unroll
  for (int i = 0; i < 16; i++) v += part[i * 256 + t];
  s[t] = v;
  __syncthreads();
  for (int st = 128; st > 0; st >>= 1) {
    if (t < st) s[t] += s[t + st];
    __syncthreads();
  }
  if (t == 0) outAux[0] = s[0] * (1.f / (float)NTOK);
}

// ---------------- exact top-k per expert ----------------
__global__ __launch_bounds__(1024) void k_topk(const float* __restrict__ probsT,
                                               int* __restrict__ idx,
                                               float* __restrict__ wts) {
  int e = blockIdx.x;
  const float* row = probsT + (size_t)e * NTOK;
  int t = threadIdx.x;
  unsigned u[16];
#pragma unroll
  for (int j = 0; j < 16; j++) u[j] = __float_as_uint(row[j * 1024 + t]);
  __shared__ int wred[16];
  __shared__ int bc;
  __shared__ int cnt_gt, cnt_eq;
  __shared__ int eqbuf[2048];
  int lane = t & 63, wv = t >> 6;
  unsigned prefix = 0;
  for (int bit = 30; bit >= 0; bit--) {
    unsigned cand = prefix | (1u << bit);
    int c = 0;
#pragma unroll
    for (int j = 0; j < 16; j++) c += (u[j] >= cand) ? 1 : 0;
#pragma unroll
    for (int s = 1; s < 64; s <<= 1) c += __shfl_xor(c, s);
    if (lane == 0) wred[wv] = c;
    __syncthreads();
    if (t == 0) { int tot = 0; for (int k = 0; k < 16; k++) tot += wred[k]; bc = tot; }
    __syncthreads();
    if (bc >= CAP) prefix = cand;
  }
  unsigned vC = prefix;
  if (t == 0) { cnt_gt = 0; cnt_eq = 0; }
  __syncthreads();
#pragma unroll
  for (int j = 0; j < 16; j++) {
    int i = j * 1024 + t;
    if (u[j] > vC) {
      int p = atomicAdd(&cnt_gt, 1);
      idx[e * CAP + p] = i;
      wts[e * CAP + p] = __uint_as_float(u[j]);
    } else if (u[j] == vC) {
      int p = atomicAdd(&cnt_eq, 1);
      if (p < 2048) eqbuf[p] = i;
    }
  }
  __syncthreads();
  int m = cnt_gt;
  int ne = cnt_eq > 2048 ? 2048 : cnt_eq;
  int needed = CAP - m;
  for (int j = t; j < ne; j += 1024) {
    int my = eqbuf[j];
    int rank = 0;
    for (int k = 0; k < ne; k++) rank += (eqbuf[k] < my) ? 1 : 0;
    if (rank < needed) {
      idx[e * CAP + m + rank] = my;
      wts[e * CAP + m + rank] = __uint_as_float(vC);
    }
  }
}

// ---------------- gather selected tokens -> bf16 ----------------
__global__ void k_gather(const float* __restrict__ hidden, const int* __restrict__ idx,
                         bf16* __restrict__ X) {
  int ec = blockIdx.x;
  int token = idx[ec];
  const float4* src = (const float4*)(hidden + (size_t)token * DM);
  bf16* dstrow = X + (size_t)ec * DM;
  int t = threadIdx.x;
  float4 v = src[t];
  bf16x4 o = {(bf16)v.x, (bf16)v.y, (bf16)v.z, (bf16)v.w};
  *(bf16x4*)(dstrow + t * 4) = o;
}

// ---------------- CONTROL ARM (unchanged r6): m97-style 128x128, single-buffer ---------
// GEMM1 only. EPI0: e x (20 bx x 32 by), KD=DM, NT=16, H = gelu(X*W1T) [grid 5120]
__global__ __launch_bounds__(256) void k_gemm128(
    const bf16* __restrict__ Ab, const bf16* __restrict__ Bb,
    bf16* __restrict__ Hb, int serialE) {
  constexpr int KD = DM;
  constexpr int NT = 16;

  __shared__ bf16 As[128 * 64];
  __shared__ bf16 Bs[128 * 64];

  int e, j;
  if (serialE >= 0) { e = serialE; j = blockIdx.x; }
  else { e = blockIdx.x & 7; j = blockIdx.x >> 3; }
  int bx = j % 20, jr = j / 20;
  int m0 = bx * 128, n0 = jr * 128;

  const bf16* A = Ab + (size_t)e * ((size_t)CAP * KD) + (size_t)m0 * KD;
  const bf16* B = Bb + (size_t)e * ((size_t)DFF * DM) + (size_t)n0 * KD;

  int t = threadIdx.x, lane = t & 63, wv = t >> 6;
  int wm = wv >> 1, wn = wv & 1;
  int l3 = lane >> 3, l7 = lane & 7;
  int cswz = (l7 ^ l3) * 8;

  f32x4 acc[4][4];
#pragma unroll
  for (int m = 0; m < 4; m++)
#pragma unroll
    for (int n = 0; n < 4; n++) acc[m][n] = (f32x4){0.f, 0.f, 0.f, 0.f};

  const bf16* gA0 = A + (size_t)(wv * 32 + l3) * KD + cswz;
  const bf16* gB0 = B + (size_t)(wv * 32 + l3) * KD + cswz;
  bf16* lA0 = As + wv * 2048 + lane * 8;
  bf16* lB0 = Bs + wv * 2048 + lane * 8;

  for (int kt = 0; kt < NT; kt++) {
    int ke = kt * 64;
#pragma unroll
    for (int jj = 0; jj < 4; jj++) {
      gl16(gA0 + (size_t)jj * 8 * KD + ke, lA0 + jj * 512);
      gl16(gB0 + (size_t)jj * 8 * KD + ke, lB0 + jj * 512);
    }
    __syncthreads();
#pragma unroll
    for (int kk = 0; kk < 2; kk++) {
      int kslot = kk * 4 + (lane >> 4);
      int slt = (kslot ^ l7) * 16;
      bf16x8 af[4], bfm[4];
#pragma unroll
      for (int m = 0; m < 4; m++) {
        int rr = wm * 64 + m * 16 + (lane & 15);
        af[m] = *(const bf16x8*)((const char*)As + rr * 128 + slt);
      }
#pragma unroll
      for (int n = 0; n < 4; n++) {
        int rr = wn * 64 + n * 16 + (lane & 15);
        bfm[n] = *(const bf16x8*)((const char*)Bs + rr * 128 + slt);
      }
#pragma unroll
      for (int m = 0; m < 4; m++)
#pragma unroll
        for (int n = 0; n < 4; n++)
          acc[m][n] = __builtin_amdgcn_mfma_f32_16x16x32_bf16(af[m], bfm[n], acc[m][n], 0, 0, 0);
    }
    __syncthreads();
  }

  int cl = lane & 15, rg = (lane >> 4) * 4;
  bf16* He = Hb + (size_t)e * CAP * DFF;
#pragma unroll
  for (int m = 0; m < 4; m++) {
    int rowg = m0 + wm * 64 + m * 16 + rg;
#pragma unroll
    for (int n = 0; n < 4; n++) {
      int col = n0 + wn * 64 + n * 16 + cl;
#pragma unroll
      for (int rr = 0; rr < 4; rr++)
        He[(size_t)(rowg + rr) * DFF + col] = (bf16)gelu_f(acc[m][n][rr]);
    }
  }
}

// ---------------- TEST ARM: minimum 2-phase dbuf 128x128 (GEMM2, ksplit=1) -------------
// Per K-tile: STAGE(next->buf^1) FIRST, then counted vmcnt(8) (prev tile landed), barrier,
// 16 asm ds_read from buf[cur], lgkmcnt(0)+sched_barrier, barrier (buf release), 32 MFMA.
// Loads for tile t+1 stay in flight through tile t's MFMA phase — no drain-to-0 in loop.
// KD=DFF, NT=64 (full K, no split): atomics halve vs r6, epilogue amortized 4x.
// Grid 1280 (e=bid&7 -> XCD, 20 bx x 8 by per expert). LDS 64 KiB -> 2 blocks/CU.
__global__ __launch_bounds__(256) void k_gemm2ph(
    const bf16* __restrict__ Hb, const bf16* __restrict__ Bb,
    const int* __restrict__ idxb, const float* __restrict__ wtsb,
    float* __restrict__ outb, int serialE) {
  constexpr int KD = DFF;
  constexpr int NT = 64;

  __shared__ bf16 As[2][128 * 64];
  __shared__ bf16 Bs[2][128 * 64];

  int e, j;
  if (serialE >= 0) { e = serialE; j = blockIdx.x; }
  else { e = blockIdx.x & 7; j = blockIdx.x >> 3; }
  int bx = j % 20, by = j / 20;
  int m0 = bx * 128, n0 = by * 128;

  const bf16* A = Hb + (size_t)e * CAP * DFF + (size_t)m0 * KD;
  const bf16* B = Bb + (size_t)e * DM * DFF + (size_t)n0 * KD;

  int t = threadIdx.x, lane = t & 63, wv = t >> 6;
  int wm = wv >> 1, wn = wv & 1;
  int l3 = lane >> 3, l7 = lane & 7;
  int cswz = (l7 ^ l3) * 8;

  const bf16* gA0 = A + (size_t)(wv * 32 + l3) * KD + cswz;
  const bf16* gB0 = B + (size_t)(wv * 32 + l3) * KD + cswz;

  f32x4 acc[4][4];
#pragma unroll
  for (int m = 0; m < 4; m++)
#pragma unroll
    for (int n = 0; n < 4; n++) acc[m][n] = (f32x4){0.f, 0.f, 0.f, 0.f};

  auto STAGE = [&](int buf, int ke) {
    bf16* lA = &As[buf][wv * 2048 + lane * 8];
    bf16* lB = &Bs[buf][wv * 2048 + lane * 8];
#pragma unroll
    for (int jj = 0; jj < 4; jj++) {
      gl16(gA0 + (size_t)jj * 8 * KD + ke, lA + jj * 512);
      gl16(gB0 + (size_t)jj * 8 * KD + ke, lB + jj * 512);
    }
  };

  STAGE(0, 0);  // prologue: 8 loads in flight

  for (int kt = 0; kt < NT; kt++) {
    int cur = kt & 1;
    if (kt < NT - 1) {
      STAGE(cur ^ 1, (kt + 1) * 64);            // 8 more; outstanding <= 16
      asm volatile("s_waitcnt vmcnt(8)");       // tile kt landed (oldest 8)
    } else {
      asm volatile("s_waitcnt vmcnt(0)");
    }
    __builtin_amdgcn_s_barrier();               // all waves: buf[cur] ready

    bf16x8 af[4][2], bfm[4][2];
#pragma unroll
    for (int kk = 0; kk < 2; kk++) {
      int kslot = kk * 4 + (lane >> 4);
      int slt = (kslot ^ l7) * 16;
#pragma unroll
      for (int m = 0; m < 4; m++) {
        int rr = wm * 64 + m * 16 + (lane & 15);
        af[m][kk] = ldsrd16((const bf16*)((const char*)&As[cur][0] + rr * 128 + slt));
      }
#pragma unroll
      for (int n = 0; n < 4; n++) {
        int rr = wn * 64 + n * 16 + (lane & 15);
        bfm[n][kk] = ldsrd16((const bf16*)((const char*)&Bs[cur][0] + rr * 128 + slt));
      }
    }
    asm volatile("s_waitcnt lgkmcnt(0)");
    __builtin_amdgcn_sched_barrier(0);
    __builtin_amdgcn_s_barrier();               // all reads done: buf[cur] may be restaged

#pragma unroll
    for (int kk = 0; kk < 2; kk++)
#pragma unroll
      for (int m = 0; m < 4; m++)
#pragma unroll
        for (int n = 0; n < 4; n++)
          acc[m][n] = __builtin_amdgcn_mfma_f32_16x16x32_bf16(af[m][kk], bfm[n][kk], acc[m][n], 0, 0, 0);
  }

  int cl = lane & 15, rg = (lane >> 4) * 4;
  const int* idxE = idxb + e * CAP;
  const float* wtsE = wtsb + e * CAP;
#pragma unroll
  for (int m = 0; m < 4; m++) {
    int rowg = m0 + wm * 64 + m * 16 + rg;
#pragma unroll
    for (int rr = 0; rr < 4; rr++) {
      int c = rowg + rr;
      int token = idxE[c];
      float w = wtsE[c];
      float* op = outb + (size_t)token * DM + n0 + wn * 64 + cl;
#pragma unroll
      for (int n = 0; n < 4; n++) atomicAdd(op + n * 16, w * acc[m][n][rr]);
    }
  }
}

extern "C" void kernel_launch(void* const* d_in, const int* in_sizes, int n_in,
                              void* d_out, int out_size, void* d_ws, size_t ws_size,
                              hipStream_t stream) {
  const float* hidden = (const float*)d_in[0];
  const float* router_w = (const float*)d_in[1];
  const float* W1 = (const float*)d_in[2];
  const float* W2 = (const float*)d_in[3];
  float* out = (float*)d_out;
  if (ws_size < WS_MIN) return;

  char* ws = (char*)d_ws;
  float* probsT = (float*)(ws + OFF_PROBS);
  int* idxb = (int*)(ws + OFF_IDX);
  float* wtsb = (float*)(ws + OFF_WTS);
  bf16* W1T = (bf16*)(ws + OFF_W1T);
  bf16* W2T = (bf16*)(ws + OFF_W2T);
  bf16* Xall = (bf16*)(ws + OFF_X);
  float* entPart = (float*)(ws + OFF_ENT);
  bf16* Hbuf = (bf16*)(ws + OFF_H);

  hipMemsetAsync(d_out, 0, (size_t)out_size * sizeof(float), stream);

  k_transpose_cvt<<<dim3(DFF / 64, DM / 64, NEXP), 256, 0, stream>>>(W1, W1T, DM, DFF);
  k_transpose_cvt<<<dim3(DM / 64, DFF / 64, NEXP), 256, 0, stream>>>(W2, W2T, DFF, DM);

  k_router<<<NTOK / 4, 256, 0, stream>>>(hidden, router_w, probsT, entPart);
  k_aux<<<1, 256, 0, stream>>>(entPart, out + (size_t)NTOK * DM);
  k_topk<<<NEXP, 1024, 0, stream>>>(probsT, idxb, wtsb);
  k_gather<<<NEXP * CAP, 256, 0, stream>>>(hidden, idxb, Xall);

  if (ws_size >= WS_FUSED) {
    k_gemm128<<<NEXP * 20 * 32, 256, 0, stream>>>(Xall, W1T, Hbuf, -1);
    k_gemm2ph<<<NEXP * 20 * 8, 256, 0, stream>>>(Hbuf, W2T, idxb, wtsb, out, -1);
  } else {
    for (int e = 0; e < NEXP; e++) {
      bf16* Hadj = Hbuf - (size_t)e * CAP * DFF;  // cancels the e-offset inside the kernel
      k_gemm128<<<20 * 32, 256, 0, stream>>>(Xall, W1T, Hadj, e);
      k_gemm2ph<<<20 * 8, 256, 0, stream>>>(Hadj, W2T, idxb, wtsb, out, e);
    }
  }
}

// Round 8
// 590.552 us; speedup vs baseline: 1.2159x; 1.0460x over previous
//
#include <hip/hip_runtime.h>
#include <hip/hip_bf16.h>
#include <math.h>

#define NTOK 16384
#define DM 1024
#define DFF 4096
#define NEXP 8
#define CAP 2560

typedef __bf16 bf16;
typedef float f32x4 __attribute__((ext_vector_type(4)));
typedef bf16 bf16x8 __attribute__((ext_vector_type(8)));
typedef bf16 bf16x4 __attribute__((ext_vector_type(4)));

// ---------------- workspace layout (bytes) ----------------
#define OFF_PROBS 0ull                 // E*N f32          = 524288
#define OFF_IDX   524288ull            // E*CAP i32        = 81920
#define OFF_WTS   606208ull            // E*CAP f32        = 81920
#define OFF_W1T   688128ull            // E*F*D bf16       = 67108864
#define OFF_W2T   67796992ull          // E*D*F bf16       = 67108864
#define OFF_X     134905856ull         // E*CAP*D bf16     = 41943040
#define OFF_ENT   OFF_X                // 4096 f32 (overlay: dead before gather writes X)
#define OFF_H     176848896ull         // fused: E*CAP*F bf16 = 167772160
#define WS_MIN    197820416ull
#define WS_FUSED  344621056ull

__device__ __forceinline__ void gl16(const bf16* g, const bf16* l) {
  __builtin_amdgcn_global_load_lds((const __attribute__((address_space(1))) void*)g,
                                   (__attribute__((address_space(3))) void*)l, 16, 0, 0);
}

// inline-asm ds_read_b128: invisible to the compiler's LDS-DMA alias tracking, so it
// cannot re-insert a vmcnt(0) drain before fragment reads while staging loads are in
// flight. Ordering enforced by explicit counted vmcnt + lgkmcnt(N)+sched_barrier.
__device__ __forceinline__ bf16x8 ldsrd16(const bf16* a) {
  bf16x8 d;
  asm volatile("ds_read_b128 %0, %1"
               : "=v"(d)
               : "v"((const __attribute__((address_space(3))) bf16*)a));
  return d;
}

__device__ __forceinline__ float gelu_f(float x) {
  // tanh-approx GELU via sigmoid; |err vs erf-gelu| < 4e-4 (validated r1-r7, absmax 2e-3)
  float u = 1.5957691216057308f * (x + 0.044715f * x * x * x);
  return x * __builtin_amdgcn_rcpf(1.f + __expf(-u));
}

// ---------------- transpose + convert fp32 -> bf16 ----------------
__global__ __launch_bounds__(256) void k_transpose_cvt(const float* __restrict__ src,
                                                       bf16* __restrict__ dst, int R, int C) {
  __shared__ float tile[64][69];
  int e = blockIdx.z;
  src += (size_t)e * R * C;
  dst += (size_t)e * R * C;
  int c0 = blockIdx.x * 64, r0 = blockIdx.y * 64;
  int t = threadIdx.x;
  int tr = t >> 4, tc4 = (t & 15) * 4;
#pragma unroll
  for (int i = 0; i < 4; i++) {
    int r = tr + i * 16;
    float4 v = *(const float4*)(src + (size_t)(r0 + r) * C + c0 + tc4);
    tile[r][tc4] = v.x; tile[r][tc4 + 1] = v.y; tile[r][tc4 + 2] = v.z; tile[r][tc4 + 3] = v.w;
  }
  __syncthreads();
#pragma unroll
  for (int i = 0; i < 4; i++) {
    int orr = tr + i * 16;
    bf16x4 o = {(bf16)tile[tc4][orr], (bf16)tile[tc4 + 1][orr],
                (bf16)tile[tc4 + 2][orr], (bf16)tile[tc4 + 3][orr]};
    *(bf16x4*)(dst + (size_t)(c0 + orr) * R + r0 + tc4) = o;
  }
}

// ---------------- router (fp-order stable since r1: selection set must be exact) --------
__global__ __launch_bounds__(256) void k_router(const float* __restrict__ hidden,
                                                const float* __restrict__ rw,
                                                float* __restrict__ probsT,
                                                float* __restrict__ entPart) {
  __shared__ float went[4];
  int wv = threadIdx.x >> 6, lane = threadIdx.x & 63;
  int token = blockIdx.x * 4 + wv;
  float acc[NEXP];
#pragma unroll
  for (int e = 0; e < NEXP; e++) acc[e] = 0.f;
  const float* hp = hidden + (size_t)token * DM;
  for (int d = lane; d < DM; d += 64) {
    float h = hp[d];
#pragma unroll
    for (int e = 0; e < NEXP; e++) acc[e] = fmaf(h, rw[d * NEXP + e], acc[e]);
  }
#pragma unroll
  for (int e = 0; e < NEXP; e++) {
    float v = acc[e];
#pragma unroll
    for (int s = 1; s < 64; s <<= 1) v += __shfl_xor(v, s);
    acc[e] = v;
  }
  float mx = acc[0];
#pragma unroll
  for (int e = 1; e < NEXP; e++) mx = fmaxf(mx, acc[e]);
  float p[NEXP], s = 0.f;
#pragma unroll
  for (int e = 0; e < NEXP; e++) { p[e] = expf(acc[e] - mx); s += p[e]; }
  float inv = 1.f / s;
  float ent = 0.f;
#pragma unroll
  for (int e = 0; e < NEXP; e++) { p[e] *= inv; ent += p[e] * logf(p[e] + 1e-8f); }
  if (lane < NEXP) probsT[(size_t)lane * NTOK + token] = p[lane];
  if (lane == 0) went[wv] = ent;
  __syncthreads();
  if (threadIdx.x == 0) entPart[blockIdx.x] = went[0] + went[1] + went[2] + went[3];
}

__global__ __launch_bounds__(256) void k_aux(const float* __restrict__ part, float* __restrict__ outAux) {
  __shared__ float s[256];
  int t = threadIdx.x;
  float v = 0.f;
#pragma unroll
  for (int i = 0; i < 16; i++) v += part[i * 256 + t];
  s[t] = v;
  __syncthreads();
  for (int st = 128; st > 0; st >>= 1) {
    if (t < st) s[t] += s[t + st];
    __syncthreads();
  }
  if (t == 0) outAux[0] = s[0] * (1.f / (float)NTOK);
}

// ---------------- exact top-k per expert ----------------
__global__ __launch_bounds__(1024) void k_topk(const float* __restrict__ probsT,
                                               int* __restrict__ idx,
                                               float* __restrict__ wts) {
  int e = blockIdx.x;
  const float* row = probsT + (size_t)e * NTOK;
  int t = threadIdx.x;
  unsigned u[16];
#pragma unroll
  for (int j = 0; j < 16; j++) u[j] = __float_as_uint(row[j * 1024 + t]);
  __shared__ int wred[16];
  __shared__ int bc;
  __shared__ int cnt_gt, cnt_eq;
  __shared__ int eqbuf[2048];
  int lane = t & 63, wv = t >> 6;
  unsigned prefix = 0;
  for (int bit = 30; bit >= 0; bit--) {
    unsigned cand = prefix | (1u << bit);
    int c = 0;
#pragma unroll
    for (int j = 0; j < 16; j++) c += (u[j] >= cand) ? 1 : 0;
#pragma unroll
    for (int s = 1; s < 64; s <<= 1) c += __shfl_xor(c, s);
    if (lane == 0) wred[wv] = c;
    __syncthreads();
    if (t == 0) { int tot = 0; for (int k = 0; k < 16; k++) tot += wred[k]; bc = tot; }
    __syncthreads();
    if (bc >= CAP) prefix = cand;
  }
  unsigned vC = prefix;
  if (t == 0) { cnt_gt = 0; cnt_eq = 0; }
  __syncthreads();
#pragma unroll
  for (int j = 0; j < 16; j++) {
    int i = j * 1024 + t;
    if (u[j] > vC) {
      int p = atomicAdd(&cnt_gt, 1);
      idx[e * CAP + p] = i;
      wts[e * CAP + p] = __uint_as_float(u[j]);
    } else if (u[j] == vC) {
      int p = atomicAdd(&cnt_eq, 1);
      if (p < 2048) eqbuf[p] = i;
    }
  }
  __syncthreads();
  int m = cnt_gt;
  int ne = cnt_eq > 2048 ? 2048 : cnt_eq;
  int needed = CAP - m;
  for (int j = t; j < ne; j += 1024) {
    int my = eqbuf[j];
    int rank = 0;
    for (int k = 0; k < ne; k++) rank += (eqbuf[k] < my) ? 1 : 0;
    if (rank < needed) {
      idx[e * CAP + m + rank] = my;
      wts[e * CAP + m + rank] = __uint_as_float(vC);
    }
  }
}

// ---------------- gather selected tokens -> bf16 ----------------
__global__ void k_gather(const float* __restrict__ hidden, const int* __restrict__ idx,
                         bf16* __restrict__ X) {
  int ec = blockIdx.x;
  int token = idx[ec];
  const float4* src = (const float4*)(hidden + (size_t)token * DM);
  bf16* dstrow = X + (size_t)ec * DM;
  int t = threadIdx.x;
  float4 v = src[t];
  bf16x4 o = {(bf16)v.x, (bf16)v.y, (bf16)v.z, (bf16)v.w};
  *(bf16x4*)(dstrow + t * 4) = o;
}

// ---------------- 2-phase dbuf MFMA GEMM, big tiles (r7 schedule, halved staging) ------
// 512 threads (8 waves). Per K-tile: STAGE(next->buf^1) first, counted vmcnt(S), barrier,
// asm ds_read frags, lgkmcnt+sched_barrier, barrier, MFMA. Loads in flight across phases.
// EPI0 (GEMM1): BM=256,BN=256, waves 2x4 (wave tile 128x64), KD=DM, NT=16, gelu->H.
//               grid e x (10bx x 16by) = 1280. LDS 128 KiB.
// EPI1 (GEMM2): BM=256,BN=128, waves 4x2 (wave tile 64x64), KD=DFF, NT=64, atomic scatter.
//               grid e x (10bx x 8by) = 640. LDS 96 KiB. ksplit=1 (atomics halved vs r7).
template <int EPI, int BM, int BN, int WMW, int WNW, int NT, int KD>
__global__ __launch_bounds__(512) void k_gemm2ph(
    const bf16* __restrict__ Ab, const bf16* __restrict__ Bb,
    bf16* __restrict__ Hb, const int* __restrict__ idxb, const float* __restrict__ wtsb,
    float* __restrict__ outb, int serialE) {
  constexpr int MF = (BM / WMW) / 16;     // m-frags per wave
  constexpr int NF = (BN / WNW) / 16;     // n-frags per wave
  constexpr int CA = BM / 8;              // A chunks (1KB each)
  constexpr int CB = BN / 8;              // B chunks
  constexpr int S = (CA + CB) / 8;        // gl16 per thread per tile
  constexpr bool SPLIT = (MF + NF) <= 8;  // split-kk overlap iff frag regs allow

  __shared__ bf16 As[2][BM * 64];
  __shared__ bf16 Bs[2][BN * 64];

  int e, j;
  if (serialE >= 0) { e = serialE; j = blockIdx.x; }
  else { e = blockIdx.x & 7; j = blockIdx.x >> 3; }
  int m0 = (j % 10) * 256;
  int n0 = (j / 10) * BN;

  const bf16* A = Ab + (size_t)e * CAP * KD + (size_t)m0 * KD;
  const bf16* B = Bb + (size_t)e * DFF * DM + (size_t)n0 * KD;

  int t = threadIdx.x, lane = t & 63, wv = t >> 6;
  int wm = wv / WNW, wn = wv % WNW;
  int l3 = lane >> 3, l7 = lane & 7, l15 = lane & 15, khalf = lane >> 4;
  int cswz = (l7 ^ l3) * 8;  // pre-swizzled global col offset (elems)

  const bf16* gA0 = A + (size_t)l3 * KD + cswz;
  const bf16* gB0 = B + (size_t)l3 * KD + cswz;

  f32x4 acc[MF][NF];
#pragma unroll
  for (int m = 0; m < MF; m++)
#pragma unroll
    for (int n = 0; n < NF; n++) acc[m][n] = (f32x4){0.f, 0.f, 0.f, 0.f};

  auto STAGE = [&](int buf, int ke) {
#pragma unroll
    for (int s = 0; s < S; s++) {
      int c = wv + s * 8;
      if (c < CA) gl16(gA0 + (size_t)(c * 8) * KD + ke, &As[buf][c * 512 + lane * 8]);
      else gl16(gB0 + (size_t)((c - CA) * 8) * KD + ke, &Bs[buf][(c - CA) * 512 + lane * 8]);
    }
  };

  STAGE(0, 0);  // prologue: S loads in flight

  int rowA = wm * (BM / WMW) + l15;
  int rowB = wn * (BN / WNW) + l15;

  for (int kt = 0; kt < NT; kt++) {
    int cur = kt & 1;
    if (kt < NT - 1) {
      STAGE(cur ^ 1, (kt + 1) * 64);            // outstanding <= 2S
      asm volatile("s_waitcnt vmcnt(%0)" :: "n"(S));  // tile kt landed (oldest S)
    } else {
      asm volatile("s_waitcnt vmcnt(0)");
    }
    __builtin_amdgcn_s_barrier();               // all waves: buf[cur] ready

    const char* Ap = (const char*)&As[cur][0];
    const char* Bp = (const char*)&Bs[cur][0];
    int slt0 = ((0 + khalf) ^ l7) * 16;
    int slt1 = ((4 + khalf) ^ l7) * 16;
    bf16x8 aF[MF][2], bF[NF][2];

    if constexpr (SPLIT) {
      // issue all 2*(MF+NF) reads; overlap MFMA kk0 with kk1 reads in flight
#pragma unroll
      for (int m = 0; m < MF; m++) aF[m][0] = ldsrd16((const bf16*)(Ap + (rowA + m * 16) * 128 + slt0));
#pragma unroll
      for (int n = 0; n < NF; n++) bF[n][0] = ldsrd16((const bf16*)(Bp + (rowB + n * 16) * 128 + slt0));
#pragma unroll
      for (int m = 0; m < MF; m++) aF[m][1] = ldsrd16((const bf16*)(Ap + (rowA + m * 16) * 128 + slt1));
#pragma unroll
      for (int n = 0; n < NF; n++) bF[n][1] = ldsrd16((const bf16*)(Bp + (rowB + n * 16) * 128 + slt1));
      asm volatile("s_waitcnt lgkmcnt(%0)" :: "n"(MF + NF));
      __builtin_amdgcn_sched_barrier(0);
#pragma unroll
      for (int m = 0; m < MF; m++)
#pragma unroll
        for (int n = 0; n < NF; n++)
          acc[m][n] = __builtin_amdgcn_mfma_f32_16x16x32_bf16(aF[m][0], bF[n][0], acc[m][n], 0, 0, 0);
      asm volatile("s_waitcnt lgkmcnt(0)");
      __builtin_amdgcn_sched_barrier(0);
      __builtin_amdgcn_s_barrier();             // all reads done: buf may be restaged
#pragma unroll
      for (int m = 0; m < MF; m++)
#pragma unroll
        for (int n = 0; n < NF; n++)
          acc[m][n] = __builtin_amdgcn_mfma_f32_16x16x32_bf16(aF[m][1], bF[n][1], acc[m][n], 0, 0, 0);
    } else {
      // two-drain form (12 frags live max — register-safe for MF=8)
#pragma unroll
      for (int m = 0; m < MF; m++) aF[m][0] = ldsrd16((const bf16*)(Ap + (rowA + m * 16) * 128 + slt0));
#pragma unroll
      for (int n = 0; n < NF; n++) bF[n][0] = ldsrd16((const bf16*)(Bp + (rowB + n * 16) * 128 + slt0));
      asm volatile("s_waitcnt lgkmcnt(0)");
      __builtin_amdgcn_sched_barrier(0);
#pragma unroll
      for (int m = 0; m < MF; m++)
#pragma unroll
        for (int n = 0; n < NF; n++)
          acc[m][n] = __builtin_amdgcn_mfma_f32_16x16x32_bf16(aF[m][0], bF[n][0], acc[m][n], 0, 0, 0);
#pragma unroll
      for (int m = 0; m < MF; m++) aF[m][1] = ldsrd16((const bf16*)(Ap + (rowA + m * 16) * 128 + slt1));
#pragma unroll
      for (int n = 0; n < NF; n++) bF[n][1] = ldsrd16((const bf16*)(Bp + (rowB + n * 16) * 128 + slt1));
      asm volatile("s_waitcnt lgkmcnt(0)");
      __builtin_amdgcn_sched_barrier(0);
      __builtin_amdgcn_s_barrier();             // all reads done: buf may be restaged
#pragma unroll
      for (int m = 0; m < MF; m++)
#pragma unroll
        for (int n = 0; n < NF; n++)
          acc[m][n] = __builtin_amdgcn_mfma_f32_16x16x32_bf16(aF[m][1], bF[n][1], acc[m][n], 0, 0, 0);
    }
  }

  int cl = lane & 15, rg = (lane >> 4) * 4;
  if constexpr (EPI == 0) {
    bf16* He = Hb + (size_t)e * CAP * DFF;
#pragma unroll
    for (int m = 0; m < MF; m++) {
      int rowg = m0 + wm * (BM / WMW) + m * 16 + rg;
#pragma unroll
      for (int n = 0; n < NF; n++) {
        int col = n0 + wn * (BN / WNW) + n * 16 + cl;
#pragma unroll
        for (int rr = 0; rr < 4; rr++)
          He[(size_t)(rowg + rr) * DFF + col] = (bf16)gelu_f(acc[m][n][rr]);
      }
    }
  } else {
    const int* idxE = idxb + e * CAP;
    const float* wtsE = wtsb + e * CAP;
#pragma unroll
    for (int m = 0; m < MF; m++) {
      int rowg = m0 + wm * (BM / WMW) + m * 16 + rg;
#pragma unroll
      for (int rr = 0; rr < 4; rr++) {
        int c = rowg + rr;
        int token = idxE[c];
        float w = wtsE[c];
        float* op = outb + (size_t)token * DM + n0 + wn * (BN / WNW) + cl;
#pragma unroll
        for (int n = 0; n < NF; n++) atomicAdd(op + n * 16, w * acc[m][n][rr]);
      }
    }
  }
}

extern "C" void kernel_launch(void* const* d_in, const int* in_sizes, int n_in,
                              void* d_out, int out_size, void* d_ws, size_t ws_size,
                              hipStream_t stream) {
  const float* hidden = (const float*)d_in[0];
  const float* router_w = (const float*)d_in[1];
  const float* W1 = (const float*)d_in[2];
  const float* W2 = (const float*)d_in[3];
  float* out = (float*)d_out;
  if (ws_size < WS_MIN) return;

  char* ws = (char*)d_ws;
  float* probsT = (float*)(ws + OFF_PROBS);
  int* idxb = (int*)(ws + OFF_IDX);
  float* wtsb = (float*)(ws + OFF_WTS);
  bf16* W1T = (bf16*)(ws + OFF_W1T);
  bf16* W2T = (bf16*)(ws + OFF_W2T);
  bf16* Xall = (bf16*)(ws + OFF_X);
  float* entPart = (float*)(ws + OFF_ENT);
  bf16* Hbuf = (bf16*)(ws + OFF_H);

  hipMemsetAsync(d_out, 0, (size_t)out_size * sizeof(float), stream);

  k_transpose_cvt<<<dim3(DFF / 64, DM / 64, NEXP), 256, 0, stream>>>(W1, W1T, DM, DFF);
  k_transpose_cvt<<<dim3(DM / 64, DFF / 64, NEXP), 256, 0, stream>>>(W2, W2T, DFF, DM);

  k_router<<<NTOK / 4, 256, 0, stream>>>(hidden, router_w, probsT, entPart);
  k_aux<<<1, 256, 0, stream>>>(entPart, out + (size_t)NTOK * DM);
  k_topk<<<NEXP, 1024, 0, stream>>>(probsT, idxb, wtsb);
  k_gather<<<NEXP * CAP, 256, 0, stream>>>(hidden, idxb, Xall);

  if (ws_size >= WS_FUSED) {
    k_gemm2ph<0, 256, 256, 2, 4, 16, DM><<<NEXP * 160, 512, 0, stream>>>(
        Xall, W1T, Hbuf, nullptr, nullptr, nullptr, -1);
    k_gemm2ph<1, 256, 128, 4, 2, 64, DFF><<<NEXP * 80, 512, 0, stream>>>(
        Hbuf, W2T, nullptr, idxb, wtsb, out, -1);
  } else {
    for (int e = 0; e < NEXP; e++) {
      bf16* Hadj = Hbuf - (size_t)e * CAP * DFF;  // cancels the e-offset inside the kernel
      k_gemm2ph<0, 256, 256, 2, 4, 16, DM><<<160, 512, 0, stream>>>(
          Xall, W1T, Hadj, nullptr, nullptr, nullptr, e);
      k_gemm2ph<1, 256, 128, 4, 2, 64, DFF><<<80, 512, 0, stream>>>(
          Hadj, W2T, nullptr, idxb, wtsb, out, e);
    }
  }
}